// Round 13
// baseline (99.481 us; speedup 1.0000x reference)
//
#include <hip/hip_runtime.h>
#include <stdint.h>

// Causal flash-attention fwd. B=16, S=2048, D=64, fp32 in/out.
// R9  (97.1): T12 in-register softmax, 32x32 swapped QK, no P-LDS.
// R15 (96.8): depth prefetch; R16 (96.1): direct-O + bf16 partials.
// R17: key-split wave pairs. Counters (R13) showed all pipes <15% busy at
//      2.5 blocks/CU: unhidden per-wave dependency latency. Blocks stay
//      4-wave/16KB-tile (staging+partial traffic UNCHANGED) but cover 64
//      q-rows; each wave pair splits keys (half0 = old sc0 path, half1 =
//      old sc1 path), merging partial-O/ls once per job via LDS. Grid
//      640 -> 1280 = 4 blocks/CU resident = 16 waves/CU (was 10); per-wave
//      critical path halves; VGPR drops (sc1 gone).

typedef __bf16 bf16x8 __attribute__((ext_vector_type(8)));
typedef float f32x4 __attribute__((ext_vector_type(4)));
typedef float f32x16 __attribute__((ext_vector_type(16)));
typedef uint32_t u32x4 __attribute__((ext_vector_type(4)));

#define NB 16
#define SL 2048
#define DH 64

__device__ __forceinline__ __bf16 f2bf(float f) {
    uint32_t u = __builtin_bit_cast(uint32_t, f);
    u += 0x7FFFu + ((u >> 16) & 1u);          // RNE
    uint16_t h = (uint16_t)(u >> 16);
    return __builtin_bit_cast(__bf16, h);
}

__device__ __forceinline__ float bf2f(uint16_t u) {
    return __builtin_bit_cast(float, (uint32_t)u << 16);
}

__device__ __forceinline__ uint32_t cvtpk(float lo, float hi) {
    uint32_t r;
    asm("v_cvt_pk_bf16_f32 %0, %1, %2" : "=v"(r) : "v"(lo), "v"(hi));
    return r;
}

__device__ __forceinline__ void load_lds16(const void* g, void* l) {
    __builtin_amdgcn_global_load_lds(
        (const __attribute__((address_space(1))) uint32_t*)g,
        (__attribute__((address_space(3))) uint32_t*)l, 16, 0, 0);
}

// ---------------- prepass ---------------- (unchanged)
__global__ __launch_bounds__(256) void prepass(
        const float* __restrict__ K, const float* __restrict__ V,
        __bf16* __restrict__ Kb, __bf16* __restrict__ Vt) {
    __shared__ float tl[64][68];
    const int b    = blockIdx.x >> 5;
    const int tile = blockIdx.x & 31;
    const int s0   = tile << 6;
    const int t    = threadIdx.x;
    const int r    = t >> 2;
    const int c0   = (t & 3) * 16;

    const float* Kp = K + ((size_t)(b * SL + s0) + r) * DH + c0;
    float4 f0 = ((const float4*)Kp)[0], f1 = ((const float4*)Kp)[1];
    float4 f2 = ((const float4*)Kp)[2], f3 = ((const float4*)Kp)[3];
    bf16x8 w0, w1;
    w0[0]=f2bf(f0.x); w0[1]=f2bf(f0.y); w0[2]=f2bf(f0.z); w0[3]=f2bf(f0.w);
    w0[4]=f2bf(f1.x); w0[5]=f2bf(f1.y); w0[6]=f2bf(f1.z); w0[7]=f2bf(f1.w);
    w1[0]=f2bf(f2.x); w1[1]=f2bf(f2.y); w1[2]=f2bf(f2.z); w1[3]=f2bf(f2.w);
    w1[4]=f2bf(f3.x); w1[5]=f2bf(f3.y); w1[6]=f2bf(f3.z); w1[7]=f2bf(f3.w);
    __bf16* Kbp = Kb + ((size_t)(b * SL + s0) + r) * DH;
    const int j0 = c0 >> 3;
    *(bf16x8*)(Kbp + ((j0       ^ (r & 7)) * 8)) = w0;
    *(bf16x8*)(Kbp + (((j0 + 1) ^ (r & 7)) * 8)) = w1;

    const float* Vp = V + ((size_t)(b * SL + s0) + r) * DH + c0;
    ((float4*)&tl[r][c0])[0] = ((const float4*)Vp)[0];
    ((float4*)&tl[r][c0])[1] = ((const float4*)Vp)[1];
    ((float4*)&tl[r][c0])[2] = ((const float4*)Vp)[2];
    ((float4*)&tl[r][c0])[3] = ((const float4*)Vp)[3];
    __syncthreads();

    __bf16* img = Vt + ((size_t)(b * 32 + tile)) * 4096;
#pragma unroll
    for (int half = 0; half < 2; ++half) {
        const int c = half * 256 + t;
        const int d = c >> 3, slot = c & 7;
        const int jj = slot ^ (d & 7);
        bf16x8 w;
#pragma unroll
        for (int e = 0; e < 8; ++e) w[e] = f2bf(tl[jj * 8 + e][d]);
        *(bf16x8*)(img + c * 8) = w;
    }
}

// ---------------- main kernel (key-split pairs, 64 q-rows/block) -------------
__global__ __launch_bounds__(256, 4) void attn_fwd(
        const float* __restrict__ Q, const __bf16* __restrict__ Kb,
        const __bf16* __restrict__ Vt, __bf16* __restrict__ part,
        float* __restrict__ lpart, float* __restrict__ O) {
    __shared__ __align__(16) __bf16 lK[2][4096];   // 16 KB (reused as merge M)
    __shared__ __align__(16) __bf16 lV[2][4096];   // 16 KB
    __shared__ float lsP[64];
    __shared__ float lsw[64];

    // job decode: qt descending (longest chunks first).
    // q-tile = 64 rows (qt 0..31); k-tiles nt = qt+1; chunk <= 8 tiles;
    // chunks per qt = (qt>>3)+1; 80 jobs/batch, 1280 blocks.
    const int bid = blockIdx.x;
    const int b   = bid & 15;                 // b&7 -> XCD: K/V L2 locality
    const int j   = bid >> 4;                 // 0..79
    int qt, c;
    if (j < 32)       { qt = 31 - (j >> 2);              c = j & 3; }
    else if (j < 56)  { int k = j - 32; qt = 23 - k / 3;   c = k % 3; }
    else if (j < 72)  { int k = j - 56; qt = 15 - (k >> 1); c = k & 1; }
    else              { qt = 79 - j;                     c = 0; }
    const int nt  = qt + 1;
    const int nch = (qt >> 3) + 1;
    const int kt0 = c * 8;
    const int kt1 = min(kt0 + 8, nt);

    const int tid  = threadIdx.x;
    const int wave = tid >> 6, lane = tid & 63;
    const int pair = wave >> 1, half = wave & 1;
    const int h    = lane >> 5, l32 = lane & 31, x8 = lane & 7;
    const int qg   = qt * 64 + pair * 32 + l32;    // this lane's q row

    // Q B-frag (32x32x16): col=lane&31=q row, k = s4*16 + h*8 + e.
    const float QSC = 0.125f * 1.44269504088896340736f;
    bf16x8 qf[4];
    const float* qp = Q + ((size_t)b * SL + qg) * DH + h * 8;
#pragma unroll
    for (int s4 = 0; s4 < 4; ++s4) {
        float4 a0 = ((const float4*)(qp + s4 * 16))[0];
        float4 a1 = ((const float4*)(qp + s4 * 16))[1];
        qf[s4][0] = f2bf(a0.x * QSC); qf[s4][1] = f2bf(a0.y * QSC);
        qf[s4][2] = f2bf(a0.z * QSC); qf[s4][3] = f2bf(a0.w * QSC);
        qf[s4][4] = f2bf(a1.x * QSC); qf[s4][5] = f2bf(a1.y * QSC);
        qf[s4][6] = f2bf(a1.z * QSC); qf[s4][7] = f2bf(a1.w * QSC);
    }

    f32x16 acc0 = (f32x16)0.0f, acc1 = (f32x16)0.0f;   // O[q][d] halves
    float lsa0 = 0.f, lsa1 = 0.f, lsa2 = 0.f, lsa3 = 0.f;

    const __bf16* Kbase = Kb + (size_t)b * SL * DH;
    const __bf16* Vbase = Vt + (size_t)b * 32 * 4096;

    auto stage = [&](int ti) {                // tile ti (<=31) -> buffer ti&1
        const int bufi = ti & 1;
        const __bf16* Ks = Kbase + (size_t)ti * 4096;
        const __bf16* Vs = Vbase + (size_t)ti * 4096;
#pragma unroll
        for (int i2 = 0; i2 < 2; ++i2) {
            load_lds16(Ks + (size_t)(i2 * 256 + tid) * 8,
                       &lK[bufi][(i2 * 256 + wave * 64) * 8]);
            load_lds16(Vs + (size_t)(i2 * 256 + tid) * 8,
                       &lV[bufi][(i2 * 256 + wave * 64) * 8]);
        }
    };

    __builtin_amdgcn_sched_barrier(0);
    stage(kt0);
    stage(min(kt0 + 1, 31));                  // dummy-safe; keeps count uniform

    for (int kt = kt0; kt < kt1; ++kt) {
        if (kt + 1 < kt1) asm volatile("s_waitcnt vmcnt(4)" ::: "memory");
        else              asm volatile("s_waitcnt vmcnt(0)" ::: "memory");
        asm volatile("s_barrier" ::: "memory");   // all waves' tile-kt loads landed
        const __bf16* K_ = lK[kt & 1];
        const __bf16* V_ = lV[kt & 1];

        // wave 1 (pair0, key-half1): keys 32-63 of diag tile > all its rows
        const bool skip = (wave == 1) && (kt == qt);
        if (!skip) {
            // S^T = K . Q^T on THIS wave's 32 keys (half*32 .. half*32+31)
            f32x16 sc = (f32x16)0.0f;
            __builtin_amdgcn_s_setprio(1);
#pragma unroll
            for (int s4 = 0; s4 < 4; ++s4) {
                bf16x8 kf = *(const bf16x8*)&K_[(half * 32 + l32) * 64 + (((s4 * 2 + h) ^ x8) << 3)];
                sc = __builtin_amdgcn_mfma_f32_32x32x16_bf16(kf, qf[s4], sc, 0, 0, 0);
            }
            __builtin_amdgcn_s_setprio(0);

            // causal mask on the (single) diagonal tile
            if (kt == qt) {
                const int kb = kt * 64 + half * 32;
#pragma unroll
                for (int r = 0; r < 16; ++r) {
                    const int key = kb + (r & 3) + 8 * (r >> 2) + 4 * h;
                    if (key > qg) sc[r] = -1.0e30f;
                }
            }

            // P = exp2(S); 4-way ls accumulators
#pragma unroll
            for (int r = 0; r < 16; ++r) sc[r] = __builtin_amdgcn_exp2f(sc[r]);
#pragma unroll
            for (int r = 0; r < 16; r += 4) {
                lsa0 += sc[r + 0]; lsa1 += sc[r + 1];
                lsa2 += sc[r + 2]; lsa3 += sc[r + 3];
            }

            // PV A-frags for this wave's 2 key-16 groups
            bf16x8 af[2];
#pragma unroll
            for (int kk = 0; kk < 2; ++kk) {
                const int jj = kk * 8;
                uint32_t u0 = cvtpk(sc[jj + 0], sc[jj + 1]);
                uint32_t u1 = cvtpk(sc[jj + 2], sc[jj + 3]);
                uint32_t u2 = cvtpk(sc[jj + 4], sc[jj + 5]);
                uint32_t u3 = cvtpk(sc[jj + 6], sc[jj + 7]);
                auto r0 = __builtin_amdgcn_permlane32_swap(u0, u2, false, false);
                auto r1 = __builtin_amdgcn_permlane32_swap(u1, u3, false, false);
                u32x4 w; w[0] = r0[0]; w[1] = r1[0]; w[2] = r0[1]; w[3] = r1[1];
                af[kk] = __builtin_bit_cast(bf16x8, w);
            }

            // O += P . V over this wave's keys (ksg = half*2 + kk)
            __builtin_amdgcn_s_setprio(1);
#pragma unroll
            for (int kk = 0; kk < 2; ++kk) {
                const int ksg = half * 2 + kk;
                bf16x8 vf0 = *(const bf16x8*)&V_[(l32)      * 64 + ((((ksg << 1) + h) ^ x8) << 3)];
                bf16x8 vf1 = *(const bf16x8*)&V_[(32 + l32) * 64 + ((((ksg << 1) + h) ^ x8) << 3)];
                acc0 = __builtin_amdgcn_mfma_f32_32x32x16_bf16(af[kk], vf0, acc0, 0, 0, 0);
                acc1 = __builtin_amdgcn_mfma_f32_32x32x16_bf16(af[kk], vf1, acc1, 0, 0, 0);
            }
            __builtin_amdgcn_s_setprio(0);
        }

        asm volatile("s_barrier" ::: "memory");   // all waves done with buf[kt&1]
        stage(min(kt + 2, 31));                   // one group per iter (dummy ok)
    }

    asm volatile("s_waitcnt vmcnt(0)" ::: "memory");   // drain (incl. dummies)
    __syncthreads();                                   // lK/lV free for merge

    // per-lane row-sum over this wave's 32 keys (h-partner holds other 16)
    float ls = (lsa0 + lsa1) + (lsa2 + lsa3);
    ls += __shfl_xor(ls, 32);

    // ---- pair merge: half1 -> LDS, half0 accumulates ----
    float* M = (float*)lK;                    // [pair][row32][d64] = 16 KB
    if (half == 1) {
#pragma unroll
        for (int r = 0; r < 16; ++r) {
            const int crow = (r & 3) + 8 * (r >> 2) + 4 * h;
            M[(pair * 32 + crow) * 64 + l32]      = acc0[r];
            M[(pair * 32 + crow) * 64 + 32 + l32] = acc1[r];
        }
        if (h == 0) lsP[pair * 32 + l32] = ls;
    }
    __syncthreads();
    if (half == 0) {
#pragma unroll
        for (int r = 0; r < 16; ++r) {
            const int crow = (r & 3) + 8 * (r >> 2) + 4 * h;
            acc0[r] += M[(pair * 32 + crow) * 64 + l32];
            acc1[r] += M[(pair * 32 + crow) * 64 + 32 + l32];
        }
        ls += lsP[pair * 32 + l32];
        if (h == 0) lsw[pair * 32 + l32] = ls;
    }
    __syncthreads();

    if (half != 0) return;                    // half0 waves (0,2) do the epilogue

    if (nch == 1) {
        // single-chunk (qt<=7): normalize + write O directly
        float* Ob = O + ((size_t)(b * SL + qt * 64 + pair * 32)) * DH;
#pragma unroll
        for (int r = 0; r < 16; ++r) {
            const int crow = (r & 3) + 8 * (r >> 2) + 4 * h;
            const float inv = 1.0f / lsw[pair * 32 + crow];
            Ob[(size_t)crow * DH + l32]      = acc0[r] * inv;
            Ob[(size_t)crow * DH + l32 + 32] = acc1[r] * inv;
        }
        return;
    }

    // multi-chunk: bf16 partials
#pragma unroll
    for (int r = 0; r < 16; ++r) {
        const int qrow = qt * 64 + pair * 32 + (r & 3) + 8 * (r >> 2) + 4 * h;
        __bf16* pp = part + ((size_t)(b * SL + qrow) * 4 + c) * DH + l32;
        pp[0]  = f2bf(acc0[r]);
        pp[32] = f2bf(acc1[r]);
    }
    if (h == 0)
        lpart[(size_t)(b * SL + qg) * 4 + c] = ls;
}

// ---------------- combine (rows >= 512 per batch; bf16 partials) -------------
__global__ __launch_bounds__(256) void combine(
        const __bf16* __restrict__ part, const float* __restrict__ lpart,
        float* __restrict__ O) {
    const int tid = threadIdx.x;
    const int bpb = 96;
    const int b   = blockIdx.x / bpb;
    const int ri  = blockIdx.x % bpb;
    const int lrow = 512 + ri * 16 + (tid >> 4);
    const size_t r = (size_t)b * SL + lrow;
    const int d4  = tid & 15;
    const int qt  = lrow >> 6;                      // 8..31
    const int nch = (qt >> 3) + 1;                  // 2..4
    float4 s = make_float4(0.f, 0.f, 0.f, 0.f);
    float ls = 0.f;
    for (int c = 0; c < nch; ++c) {
        ushort4 u = *(const ushort4*)(part + (r * 4 + c) * DH + d4 * 4);
        s.x += bf2f(u.x); s.y += bf2f(u.y); s.z += bf2f(u.z); s.w += bf2f(u.w);
        ls += lpart[r * 4 + c];
    }
    const float inv = 1.0f / ls;
    float4 o; o.x = s.x * inv; o.y = s.y * inv; o.z = s.z * inv; o.w = s.w * inv;
    *(float4*)(O + r * DH + d4 * 4) = o;
}

extern "C" void kernel_launch(void* const* d_in, const int* in_sizes, int n_in,
                              void* d_out, int out_size, void* d_ws, size_t ws_size,
                              hipStream_t stream) {
    const float* q = (const float*)d_in[0];
    const float* k = (const float*)d_in[1];
    const float* v = (const float*)d_in[2];
    float* o = (float*)d_out;
    __bf16* Kb   = (__bf16*)d_ws;                          // 4 MiB
    __bf16* Vt   = Kb + (size_t)NB * SL * DH;              // 4 MiB
    __bf16* pt   = (__bf16*)((char*)d_ws + (8u << 20));    // 16 MiB bf16 partials
    float*  lp   = (float*)((char*)d_ws + (24u << 20));    // 512 KiB
    hipLaunchKernelGGL(prepass, dim3(NB * 32), dim3(256), 0, stream, k, v, Kb, Vt);
    hipLaunchKernelGGL(attn_fwd, dim3(1280), dim3(256), 0, stream, q, Kb, Vt, pt, lp, o);
    hipLaunchKernelGGL(combine, dim3(NB * 96), dim3(256), 0, stream, pt, lp, o);
}

// Round 14
// 96.541 us; speedup vs baseline: 1.0304x; 1.0304x over previous
//
#include <hip/hip_runtime.h>
#include <stdint.h>

// Causal flash-attention fwd. B=16, S=2048, D=64, fp32 in/out.
// R9  (97.1): T12 in-register softmax, 32x32 swapped QK, no P-LDS.
// R15 (96.8): depth-2 prefetch; R16 (96.1): direct-O + bf16 partials.
// R17 (REVERTED, 99.5): key-split doubled staged traffic (272->528 tile-iters).
// R18: register-pressure fix. R13 evidence: VGPR_Count=64 with ~150 live
//      values -> compiler cannot hoist ds_reads -> serial read->MFMA chains
//      (~1700cy/tile, all pipes <15%). (a) __launch_bounds__(256,2) lifts
//      the VGPR cap; (b) all 8 kf + 8 vf batch-loaded into named regs at
//      tile top: QK waits kf only, vf latency hides under exp2/pack.

typedef __bf16 bf16x8 __attribute__((ext_vector_type(8)));
typedef float f32x4 __attribute__((ext_vector_type(4)));
typedef float f32x16 __attribute__((ext_vector_type(16)));
typedef uint32_t u32x4 __attribute__((ext_vector_type(4)));

#define NB 16
#define SL 2048
#define DH 64

__device__ __forceinline__ __bf16 f2bf(float f) {
    uint32_t u = __builtin_bit_cast(uint32_t, f);
    u += 0x7FFFu + ((u >> 16) & 1u);          // RNE
    uint16_t h = (uint16_t)(u >> 16);
    return __builtin_bit_cast(__bf16, h);
}

__device__ __forceinline__ float bf2f(uint16_t u) {
    return __builtin_bit_cast(float, (uint32_t)u << 16);
}

__device__ __forceinline__ uint32_t cvtpk(float lo, float hi) {
    uint32_t r;
    asm("v_cvt_pk_bf16_f32 %0, %1, %2" : "=v"(r) : "v"(lo), "v"(hi));
    return r;
}

__device__ __forceinline__ void load_lds16(const void* g, void* l) {
    __builtin_amdgcn_global_load_lds(
        (const __attribute__((address_space(1))) uint32_t*)g,
        (__attribute__((address_space(3))) uint32_t*)l, 16, 0, 0);
}

// ---------------- prepass ---------------- (unchanged)
__global__ __launch_bounds__(256) void prepass(
        const float* __restrict__ K, const float* __restrict__ V,
        __bf16* __restrict__ Kb, __bf16* __restrict__ Vt) {
    __shared__ float tl[64][68];
    const int b    = blockIdx.x >> 5;
    const int tile = blockIdx.x & 31;
    const int s0   = tile << 6;
    const int t    = threadIdx.x;
    const int r    = t >> 2;
    const int c0   = (t & 3) * 16;

    const float* Kp = K + ((size_t)(b * SL + s0) + r) * DH + c0;
    float4 f0 = ((const float4*)Kp)[0], f1 = ((const float4*)Kp)[1];
    float4 f2 = ((const float4*)Kp)[2], f3 = ((const float4*)Kp)[3];
    bf16x8 w0, w1;
    w0[0]=f2bf(f0.x); w0[1]=f2bf(f0.y); w0[2]=f2bf(f0.z); w0[3]=f2bf(f0.w);
    w0[4]=f2bf(f1.x); w0[5]=f2bf(f1.y); w0[6]=f2bf(f1.z); w0[7]=f2bf(f1.w);
    w1[0]=f2bf(f2.x); w1[1]=f2bf(f2.y); w1[2]=f2bf(f2.z); w1[3]=f2bf(f2.w);
    w1[4]=f2bf(f3.x); w1[5]=f2bf(f3.y); w1[6]=f2bf(f3.z); w1[7]=f2bf(f3.w);
    __bf16* Kbp = Kb + ((size_t)(b * SL + s0) + r) * DH;
    const int j0 = c0 >> 3;
    *(bf16x8*)(Kbp + ((j0       ^ (r & 7)) * 8)) = w0;
    *(bf16x8*)(Kbp + (((j0 + 1) ^ (r & 7)) * 8)) = w1;

    const float* Vp = V + ((size_t)(b * SL + s0) + r) * DH + c0;
    ((float4*)&tl[r][c0])[0] = ((const float4*)Vp)[0];
    ((float4*)&tl[r][c0])[1] = ((const float4*)Vp)[1];
    ((float4*)&tl[r][c0])[2] = ((const float4*)Vp)[2];
    ((float4*)&tl[r][c0])[3] = ((const float4*)Vp)[3];
    __syncthreads();

    __bf16* img = Vt + ((size_t)(b * 32 + tile)) * 4096;
#pragma unroll
    for (int half = 0; half < 2; ++half) {
        const int c = half * 256 + t;
        const int d = c >> 3, slot = c & 7;
        const int jj = slot ^ (d & 7);
        bf16x8 w;
#pragma unroll
        for (int e = 0; e < 8; ++e) w[e] = f2bf(tl[jj * 8 + e][d]);
        *(bf16x8*)(img + c * 8) = w;
    }
}

// ---------------- main kernel (split-K jobs, 128 q-rows/block) ----------------
__global__ __launch_bounds__(256, 2) void attn_fwd(
        const float* __restrict__ Q, const __bf16* __restrict__ Kb,
        const __bf16* __restrict__ Vt, __bf16* __restrict__ part,
        float* __restrict__ lpart, float* __restrict__ O) {
    __shared__ __align__(16) __bf16 lK[3][4096];   // 24 KB
    __shared__ __align__(16) __bf16 lV[3][4096];   // 24 KB
    __shared__ float lsw[128];

    // job decode: j descending so long chunks dispatch first.
    const int bid = blockIdx.x;
    const int b   = bid & 15;                 // b&7 -> XCD: K/V L2 locality
    const int j   = 39 - (bid >> 4);
    int qb, c;
    if (j < 4)        { qb = j;                 c = 0; }
    else if (j < 12)  { qb = 4 + ((j - 4) >> 1);  c = (j - 4) & 1; }
    else if (j < 24)  { int k = j - 12; qb = 8 + k / 3;    c = k % 3; }
    else              { int k = j - 24; qb = 12 + (k >> 2); c = k & 3; }
    const int nt  = 2 * qb + 2;
    const int nch = (2 * qb + 9) >> 3;
    const int kt0 = c * 8;
    const int kt1 = min(kt0 + 8, nt);

    const int tid  = threadIdx.x;
    const int wave = tid >> 6, lane = tid & 63;
    const int h    = lane >> 5, l32 = lane & 31, x8 = lane & 7;
    const int qg   = qb * 128 + wave * 32 + l32;
    const int dt   = 2 * qb + (wave >> 1);

    const float QSC = 0.125f * 1.44269504088896340736f;
    bf16x8 qf[4];
    const float* qp = Q + ((size_t)b * SL + qg) * DH + h * 8;
#pragma unroll
    for (int s4 = 0; s4 < 4; ++s4) {
        float4 a0 = ((const float4*)(qp + s4 * 16))[0];
        float4 a1 = ((const float4*)(qp + s4 * 16))[1];
        qf[s4][0] = f2bf(a0.x * QSC); qf[s4][1] = f2bf(a0.y * QSC);
        qf[s4][2] = f2bf(a0.z * QSC); qf[s4][3] = f2bf(a0.w * QSC);
        qf[s4][4] = f2bf(a1.x * QSC); qf[s4][5] = f2bf(a1.y * QSC);
        qf[s4][6] = f2bf(a1.z * QSC); qf[s4][7] = f2bf(a1.w * QSC);
    }

    f32x16 acc0 = (f32x16)0.0f, acc1 = (f32x16)0.0f;
    float lsa0 = 0.f, lsa1 = 0.f, lsa2 = 0.f, lsa3 = 0.f;

    const __bf16* Kbase = Kb + (size_t)b * SL * DH;
    const __bf16* Vbase = Vt + (size_t)b * 32 * 4096;

    auto stage = [&](int ti, int bufi) {
        const __bf16* Ks = Kbase + (size_t)ti * 4096;
        const __bf16* Vs = Vbase + (size_t)ti * 4096;
#pragma unroll
        for (int i2 = 0; i2 < 2; ++i2) {
            load_lds16(Ks + (size_t)(i2 * 256 + tid) * 8,
                       &lK[bufi][(i2 * 256 + wave * 64) * 8]);
            load_lds16(Vs + (size_t)(i2 * 256 + tid) * 8,
                       &lV[bufi][(i2 * 256 + wave * 64) * 8]);
        }
    };

    __builtin_amdgcn_sched_barrier(0);
    stage(kt0, kt0 % 3);
    stage(min(kt0 + 1, 31), (kt0 + 1) % 3);
    stage(min(kt0 + 2, 31), (kt0 + 2) % 3);

    for (int kt = kt0; kt < kt1; ++kt) {
        asm volatile("s_waitcnt vmcnt(8)" ::: "memory");   // own tile landed
        asm volatile("s_barrier" ::: "memory");
        const __bf16* K_ = lK[kt % 3];
        const __bf16* V_ = lV[kt % 3];

        const bool skip = (wave < 2) && (kt == nt - 1);
        if (!skip) {
            // ---- batch ALL LDS reads first: 8 kf + 8 vf into named regs ----
            bf16x8 kf[8], vf[8];
#pragma unroll
            for (int s4 = 0; s4 < 4; ++s4) {
                kf[s4]     = *(const bf16x8*)&K_[(l32)      * 64 + (((s4 * 2 + h) ^ x8) << 3)];
                kf[4 + s4] = *(const bf16x8*)&K_[(32 + l32) * 64 + (((s4 * 2 + h) ^ x8) << 3)];
            }
#pragma unroll
            for (int ks = 0; ks < 4; ++ks) {
                vf[ks]     = *(const bf16x8*)&V_[(l32)      * 64 + ((((ks << 1) + h) ^ x8) << 3)];
                vf[4 + ks] = *(const bf16x8*)&V_[(32 + l32) * 64 + ((((ks << 1) + h) ^ x8) << 3)];
            }

            // S^T = K . Q^T (swapped): C[key][q]
            f32x16 sc0 = (f32x16)0.0f, sc1 = (f32x16)0.0f;
            __builtin_amdgcn_s_setprio(1);
#pragma unroll
            for (int s4 = 0; s4 < 4; ++s4) {
                sc0 = __builtin_amdgcn_mfma_f32_32x32x16_bf16(kf[s4],     qf[s4], sc0, 0, 0, 0);
                sc1 = __builtin_amdgcn_mfma_f32_32x32x16_bf16(kf[4 + s4], qf[s4], sc1, 0, 0, 0);
            }
            __builtin_amdgcn_s_setprio(0);

            if (kt >= dt) {                       // causal mask on diagonal tiles
                const int kb = kt * 64;
#pragma unroll
                for (int r = 0; r < 16; ++r) {
                    const int krow = (r & 3) + 8 * (r >> 2) + 4 * h;
                    if (kb + krow > qg)      sc0[r] = -1.0e30f;
                    if (kb + 32 + krow > qg) sc1[r] = -1.0e30f;
                }
            }

            // P = exp2(S); 4-way ls accumulators (vf latency hides under this)
#pragma unroll
            for (int r = 0; r < 16; ++r) {
                sc0[r] = __builtin_amdgcn_exp2f(sc0[r]);
                sc1[r] = __builtin_amdgcn_exp2f(sc1[r]);
            }
#pragma unroll
            for (int r = 0; r < 16; r += 4) {
                lsa0 += sc0[r + 0] + sc1[r + 0];
                lsa1 += sc0[r + 1] + sc1[r + 1];
                lsa2 += sc0[r + 2] + sc1[r + 2];
                lsa3 += sc0[r + 3] + sc1[r + 3];
            }

            // PV A-frags via cvt_pk + permlane32_swap
            bf16x8 af[4];
#pragma unroll
            for (int ks = 0; ks < 4; ++ks) {
                const int jj = (ks & 1) * 8;
                const f32x16& sg = (ks & 2) ? sc1 : sc0;
                uint32_t u0 = cvtpk(sg[jj + 0], sg[jj + 1]);
                uint32_t u1 = cvtpk(sg[jj + 2], sg[jj + 3]);
                uint32_t u2 = cvtpk(sg[jj + 4], sg[jj + 5]);
                uint32_t u3 = cvtpk(sg[jj + 6], sg[jj + 7]);
                auto r0 = __builtin_amdgcn_permlane32_swap(u0, u2, false, false);
                auto r1 = __builtin_amdgcn_permlane32_swap(u1, u3, false, false);
                u32x4 w; w[0] = r0[0]; w[1] = r1[0]; w[2] = r0[1]; w[3] = r1[1];
                af[ks] = __builtin_bit_cast(bf16x8, w);
            }

            // O += P . V (vf already in regs)
            __builtin_amdgcn_s_setprio(1);
#pragma unroll
            for (int ks = 0; ks < 4; ++ks) {
                acc0 = __builtin_amdgcn_mfma_f32_32x32x16_bf16(af[ks], vf[ks],     acc0, 0, 0, 0);
                acc1 = __builtin_amdgcn_mfma_f32_32x32x16_bf16(af[ks], vf[4 + ks], acc1, 0, 0, 0);
            }
            __builtin_amdgcn_s_setprio(0);
        }

        asm volatile("s_barrier" ::: "memory");   // all waves done with buf[kt%3]
        stage(min(kt + 3, 31), kt % 3);           // exactly ONE group per iter
    }

    asm volatile("s_waitcnt vmcnt(0)" ::: "memory");   // drain trailing dummies

    float ls = (lsa0 + lsa1) + (lsa2 + lsa3);
    ls += __shfl_xor(ls, 32);
    if (h == 0) lsw[wave * 32 + l32] = ls;
    __syncthreads();

    if (nch == 1) {
        // single-chunk group (qb<=3): normalize + write O directly
        float* Ob = O + ((size_t)(b * SL + qb * 128 + wave * 32)) * DH;
#pragma unroll
        for (int r = 0; r < 16; ++r) {
            const int crow = (r & 3) + 8 * (r >> 2) + 4 * h;
            const float inv = 1.0f / lsw[wave * 32 + crow];
            Ob[(size_t)crow * DH + l32]      = acc0[r] * inv;
            Ob[(size_t)crow * DH + l32 + 32] = acc1[r] * inv;
        }
        return;
    }

    // multi-chunk: bf16 partials
#pragma unroll
    for (int r = 0; r < 16; ++r) {
        const int qrow = qb * 128 + wave * 32 + (r & 3) + 8 * (r >> 2) + 4 * h;
        __bf16* pp = part + ((size_t)(b * SL + qrow) * 4 + c) * DH + l32;
        pp[0]  = f2bf(acc0[r]);
        pp[32] = f2bf(acc1[r]);
    }
    if (h == 0)
        lpart[(size_t)(b * SL + qg) * 4 + c] = ls;
}

// ---------------- combine (qb>=4 rows only; bf16 partials) ----------------
__global__ __launch_bounds__(256) void combine(
        const __bf16* __restrict__ part, const float* __restrict__ lpart,
        float* __restrict__ O) {
    const int tid = threadIdx.x;
    const int bpb = 96;
    const int b   = blockIdx.x / bpb;
    const int ri  = blockIdx.x % bpb;
    const int lrow = 512 + ri * 16 + (tid >> 4);
    const size_t r = (size_t)b * SL + lrow;
    const int d4  = tid & 15;
    const int qb  = lrow >> 7;                      // 4..15
    const int nch = (2 * qb + 9) >> 3;              // 2..4
    float4 s = make_float4(0.f, 0.f, 0.f, 0.f);
    float ls = 0.f;
    for (int c = 0; c < nch; ++c) {
        ushort4 u = *(const ushort4*)(part + (r * 4 + c) * DH + d4 * 4);
        s.x += bf2f(u.x); s.y += bf2f(u.y); s.z += bf2f(u.z); s.w += bf2f(u.w);
        ls += lpart[r * 4 + c];
    }
    const float inv = 1.0f / ls;
    float4 o; o.x = s.x * inv; o.y = s.y * inv; o.z = s.z * inv; o.w = s.w * inv;
    *(float4*)(O + r * DH + d4 * 4) = o;
}

extern "C" void kernel_launch(void* const* d_in, const int* in_sizes, int n_in,
                              void* d_out, int out_size, void* d_ws, size_t ws_size,
                              hipStream_t stream) {
    const float* q = (const float*)d_in[0];
    const float* k = (const float*)d_in[1];
    const float* v = (const float*)d_in[2];
    float* o = (float*)d_out;
    __bf16* Kb   = (__bf16*)d_ws;                          // 4 MiB
    __bf16* Vt   = Kb + (size_t)NB * SL * DH;              // 4 MiB
    __bf16* pt   = (__bf16*)((char*)d_ws + (8u << 20));    // 16 MiB bf16 partials
    float*  lp   = (float*)((char*)d_ws + (24u << 20));    // 512 KiB
    hipLaunchKernelGGL(prepass, dim3(NB * 32), dim3(256), 0, stream, k, v, Kb, Vt);
    hipLaunchKernelGGL(attn_fwd, dim3(640), dim3(256), 0, stream, q, Kb, Vt, pt, lp, o);
    hipLaunchKernelGGL(combine, dim3(NB * 96), dim3(256), 0, stream, pt, lp, o);
}